// Round 1
// baseline (6418.629 us; speedup 1.0000x reference)
//
#include <hip/hip_runtime.h>

#define SEQ 512
#define BATCH 128
#define INDIM 256
#define HID 256
#define CS 512            // HID + INDIM
#define BT 16             // batch rows per group
#define NCB 8             // col-blocks per group
#define NC 128            // gate-cols per block (4 gates x 32 hidden)
#define HS 32             // hidden slice per block
#define KSTEPS 16         // 512 / 32
#define NCT 8             // 16-wide col tiles per block
#define ZPAD 520          // z16 row stride (f16 elems)
#define GPAD 132          // gates row stride (f32 elems)
#define NTHREADS 256
#define NBLOCKS 128

typedef _Float16 f16;
typedef __attribute__((ext_vector_type(8))) _Float16 f16x8;
typedef __attribute__((ext_vector_type(4))) float f32x4;

struct Params {
  const float* X;
  const float* W[8];    // [dir*4 + gate], gate order f,i,c,o
  const float* Bv[8];
  float* out;
  f16* hbuf;            // [dir][parity][BATCH][HID]
  unsigned* ctrs;       // [16 groups] stride 64 uints
};

__device__ __forceinline__ float sigm(float x) {
  return 1.0f / (1.0f + __expf(-x));
}
__device__ __forceinline__ float tanh_fast(float x) {
  return 1.0f - 2.0f / (__expf(2.0f * x) + 1.0f);
}

// LDS layout (bytes)
#define B_OFF   0
#define B_BYTES (NCT * KSTEPS * 64 * 16)      // 131072: weights, fragment order
#define Z_OFF   (B_OFF + B_BYTES)
#define Z_BYTES (16 * ZPAD * 2)               // 16640: z = [h | x] fp16
#define G_OFF   (Z_OFF + Z_BYTES)
#define G_BYTES (16 * GPAD * 4)               // 8448: gate pre-activations fp32
#define BI_OFF  (G_OFF + G_BYTES)
#define BI_BYTES (NC * 4)                     // 512: biases
#define LDS_TOTAL (BI_OFF + BI_BYTES)         // 156672 <= 163840

__global__ void __launch_bounds__(NTHREADS, 1) blstm_persistent(Params p) {
  extern __shared__ char smem[];
  f16x8* Blds = (f16x8*)(smem + B_OFF);
  f16*   z16  = (f16*)(smem + Z_OFF);
  float* gl   = (float*)(smem + G_OFF);
  float* bi   = (float*)(smem + BI_OFF);

  const int tid = threadIdx.x;
  const int bid = blockIdx.x;
  // group members stride 8 in blockIdx -> same XCD (perf heuristic only)
  const int dir = bid >> 6;          // 0 fwd, 1 bwd
  const int cb  = (bid >> 3) & 7;    // col-block (member within group)
  const int bt  = bid & 7;           // batch tile
  const int b0  = bt * BT;
  const int j0  = cb * HS;
  unsigned* ctr = p.ctrs + (dir * 8 + bt) * 64;

  // ---- one-time: weights -> LDS in MFMA B-fragment order ----
  for (int u = tid; u < NC * 64; u += NTHREADS) {
    const int cl = u >> 6;           // local col 0..127
    const int kc = u & 63;           // 8-elem k chunk
    const int g  = cl >> 5;
    const int row = j0 + (cl & 31);
    const float* src = p.W[dir * 4 + g] + (size_t)row * CS + kc * 8;
    f16x8 v;
    #pragma unroll
    for (int j = 0; j < 8; ++j) v[j] = (f16)src[j];
    const int ct = cl >> 4;
    const int lp = cl & 15;
    const int ks = kc >> 2;
    const int kg = kc & 3;
    Blds[(ct * KSTEPS + ks) * 64 + kg * 16 + lp] = v;
  }
  if (tid < NC) {
    const int g = tid >> 5;
    bi[tid] = p.Bv[dir * 4 + g][j0 + (tid & 31)];
  }

  // persistent cell state: thread owns (m=cm, j=cj) and (cm, cj+1)
  const int cm = tid >> 4;           // 0..15
  const int cj = (tid & 15) * 2;     // 0..30 even
  float c0 = 0.0f, c1 = 0.0f;

  const int w = tid >> 6;
  const int lane = tid & 63;

  __syncthreads();

  for (int t = 0; t < SEQ; ++t) {
    const int tt  = dir ? (SEQ - 1 - t) : t;
    const int par = t & 1;
    const f16* hin = p.hbuf + (size_t)(dir * 2 + par) * (BATCH * HID);

    // stage h part (k 0..255): coherent (agent) loads bypass stale caches
    for (int u = tid; u < 2048; u += NTHREADS) {
      const int row = u >> 7;
      const int kk  = u & 127;
      unsigned* s = (unsigned*)(hin + (size_t)(b0 + row) * HID) + kk;
      unsigned v = __hip_atomic_load(s, __ATOMIC_RELAXED, __HIP_MEMORY_SCOPE_AGENT);
      *(unsigned*)(z16 + row * ZPAD + kk * 2) = v;
    }
    // stage x part (k 256..511), fp32 -> fp16
    {
      const int row = tid >> 4;
      const int k0  = (tid & 15) * 16;
      const float* xs = p.X + ((size_t)tt * BATCH + b0 + row) * INDIM + k0;
      const f32x4* xv = (const f32x4*)xs;
      f32x4 xa = xv[0], xb = xv[1], xc = xv[2], xd = xv[3];
      f16x8 v0, v1;
      #pragma unroll
      for (int j = 0; j < 4; ++j) { v0[j] = (f16)xa[j]; v0[4 + j] = (f16)xb[j]; }
      #pragma unroll
      for (int j = 0; j < 4; ++j) { v1[j] = (f16)xc[j]; v1[4 + j] = (f16)xd[j]; }
      *(f16x8*)(z16 + row * ZPAD + 256 + k0)     = v0;
      *(f16x8*)(z16 + row * ZPAD + 256 + k0 + 8) = v1;
    }
    __syncthreads();

    // MFMA: wave w owns col tiles 2w, 2w+1 (one gate per wave)
    f32x4 acc0 = {0.f, 0.f, 0.f, 0.f};
    f32x4 acc1 = {0.f, 0.f, 0.f, 0.f};
    const f16* za = z16 + (lane & 15) * ZPAD + ((lane >> 4) * 8);
    #pragma unroll
    for (int ks = 0; ks < KSTEPS; ++ks) {
      f16x8 av  = *(const f16x8*)(za + ks * 32);
      f16x8 bv0 = Blds[((2 * w)     * KSTEPS + ks) * 64 + lane];
      f16x8 bv1 = Blds[((2 * w + 1) * KSTEPS + ks) * 64 + lane];
      acc0 = __builtin_amdgcn_mfma_f32_16x16x32_f16(av, bv0, acc0, 0, 0, 0);
      acc1 = __builtin_amdgcn_mfma_f32_16x16x32_f16(av, bv1, acc1, 0, 0, 0);
    }
    // D layout (verified): col = lane&15, row = (lane>>4)*4 + reg
    #pragma unroll
    for (int r = 0; r < 4; ++r) {
      const int mr = (lane >> 4) * 4 + r;
      gl[mr * GPAD + w * 32 +      (lane & 15)] = acc0[r];
      gl[mr * GPAD + w * 32 + 16 + (lane & 15)] = acc1[r];
    }
    __syncthreads();

    // combine: gates -> c,h for owned (cm, cj), (cm, cj+1)
    {
      const float ff0 = sigm(gl[cm * GPAD +  0 + cj]     + bi[ 0 + cj]);
      const float ff1 = sigm(gl[cm * GPAD +  0 + cj + 1] + bi[ 0 + cj + 1]);
      const float ii0 = sigm(gl[cm * GPAD + 32 + cj]     + bi[32 + cj]);
      const float ii1 = sigm(gl[cm * GPAD + 32 + cj + 1] + bi[32 + cj + 1]);
      const float cc0 = tanh_fast(gl[cm * GPAD + 64 + cj]     + bi[64 + cj]);
      const float cc1 = tanh_fast(gl[cm * GPAD + 64 + cj + 1] + bi[64 + cj + 1]);
      const float oo0 = sigm(gl[cm * GPAD + 96 + cj]     + bi[96 + cj]);
      const float oo1 = sigm(gl[cm * GPAD + 96 + cj + 1] + bi[96 + cj + 1]);
      c0 = ff0 * c0 + ii0 * cc0;
      c1 = ff1 * c1 + ii1 * cc1;
      const float h0 = oo0 * tanh_fast(c0);
      const float h1 = oo1 * tanh_fast(c1);
      union { unsigned u; f16 h[2]; } pk;
      pk.h[0] = (f16)h0; pk.h[1] = (f16)h1;
      f16* hop = p.hbuf + (size_t)(dir * 2 + (par ^ 1)) * (BATCH * HID)
               + (size_t)(b0 + cm) * HID + j0 + cj;
      __hip_atomic_store((unsigned*)hop, pk.u, __ATOMIC_RELEASE, __HIP_MEMORY_SCOPE_AGENT);
      float* op = p.out + ((size_t)tt * BATCH + b0 + cm) * (2 * HID) + dir * HID + j0 + cj;
      op[0] = h0; op[1] = h1;
    }

    // group barrier: monotonic counter, one barrier/step (h is double-buffered)
    __syncthreads();                 // all h stores complete (vmcnt drained)
    if (tid == 0) {
      __hip_atomic_fetch_add(ctr, 1u, __ATOMIC_RELEASE, __HIP_MEMORY_SCOPE_AGENT);
      const unsigned tgt = (unsigned)(NCB * (t + 1));
      while (__hip_atomic_load(ctr, __ATOMIC_ACQUIRE, __HIP_MEMORY_SCOPE_AGENT) < tgt) {
        __builtin_amdgcn_s_sleep(1);
      }
    }
    __syncthreads();
  }
}

extern "C" void kernel_launch(void* const* d_in, const int* in_sizes, int n_in,
                              void* d_out, int out_size, void* d_ws, size_t ws_size,
                              hipStream_t stream) {
  (void)in_sizes; (void)n_in; (void)out_size; (void)ws_size;
  Params p;
  p.X = (const float*)d_in[0];
  for (int i = 0; i < 8; ++i) {
    p.W[i]  = (const float*)d_in[1 + 2 * i];   // Wf,Wi,Wc,Wo (fwd), then bwd
    p.Bv[i] = (const float*)d_in[2 + 2 * i];
  }
  p.out  = (float*)d_out;
  p.ctrs = (unsigned*)d_ws;
  p.hbuf = (f16*)((char*)d_ws + 4096);

  // reset barrier counters + zero h(t=0) both dirs/parities, every launch
  hipMemsetAsync(d_ws, 0, 4096 + 2 * 2 * BATCH * HID * (int)sizeof(f16), stream);

  static_assert(LDS_TOTAL <= 160 * 1024, "LDS overflow");
  hipFuncSetAttribute(reinterpret_cast<const void*>(blstm_persistent),
                      hipFuncAttributeMaxDynamicSharedMemorySize, LDS_TOTAL);
  blstm_persistent<<<NBLOCKS, NTHREADS, LDS_TOTAL, stream>>>(p);
}